// Round 5
// baseline (428.424 us; speedup 1.0000x reference)
//
#include <hip/hip_runtime.h>
#include <math.h>

#define BB 32
#define TT 100
#define VV 10000
#define DD 128
#define OUTN 1000
#define G3 384
#define CH 25    // GRU steps per LDS-staged x3 chunk
#define KS 8     // k-split factor (cols per thread = DD/KS = 16)

// ---------------------------------------------------------------------------
// K1: sparse embedding sum  e[b,t,:] = sum_{v: x!=0} x[b,t,v] * emb[v,:]
// ---------------------------------------------------------------------------
__global__ __launch_bounds__(256) void k_embed(
    const float* __restrict__ x, const float* __restrict__ emb,
    float* __restrict__ e, int* __restrict__ mask)
{
    const int bt  = blockIdx.x;
    const int tid = threadIdx.x;
    __shared__ int   s_cnt;
    __shared__ int   s_any;
    __shared__ int   s_idx[256];
    __shared__ float s_val[256];
    if (tid == 0) { s_cnt = 0; s_any = 0; }
    __syncthreads();

    const float4* x4 = (const float4*)(x + (size_t)bt * VV);
    float4 v[10];
    #pragma unroll
    for (int k = 0; k < 10; ++k) {
        int i = tid + k * 256;
        int ic = i < 2500 ? i : 2499;
        v[k] = x4[ic];
        if (i >= 2500) { v[k].x = 0.f; v[k].y = 0.f; v[k].z = 0.f; v[k].w = 0.f; }
    }
    #pragma unroll
    for (int k = 0; k < 10; ++k) {
        int base = (tid + k * 256) * 4;
        if (v[k].x != 0.f) { int p = atomicAdd(&s_cnt, 1); if (p < 256) { s_idx[p] = base+0; s_val[p] = v[k].x; } }
        if (v[k].y != 0.f) { int p = atomicAdd(&s_cnt, 1); if (p < 256) { s_idx[p] = base+1; s_val[p] = v[k].y; } }
        if (v[k].z != 0.f) { int p = atomicAdd(&s_cnt, 1); if (p < 256) { s_idx[p] = base+2; s_val[p] = v[k].z; } }
        if (v[k].w != 0.f) { int p = atomicAdd(&s_cnt, 1); if (p < 256) { s_idx[p] = base+3; s_val[p] = v[k].w; } }
    }
    __syncthreads();
    int cnt = s_cnt; if (cnt > 256) cnt = 256;
    if (tid < DD) {
        float a0 = 0.f, a1 = 0.f, a2 = 0.f, a3 = 0.f;
        int i = 0;
        for (; i + 4 <= cnt; i += 4) {
            a0 += s_val[i+0] * emb[(size_t)s_idx[i+0] * DD + tid];
            a1 += s_val[i+1] * emb[(size_t)s_idx[i+1] * DD + tid];
            a2 += s_val[i+2] * emb[(size_t)s_idx[i+2] * DD + tid];
            a3 += s_val[i+3] * emb[(size_t)s_idx[i+3] * DD + tid];
        }
        for (; i < cnt; ++i)
            a0 += s_val[i] * emb[(size_t)s_idx[i] * DD + tid];
        float acc = (a0 + a1) + (a2 + a3);
        e[(size_t)bt * DD + tid] = acc;
        if (acc != 0.f) s_any = 1;
    }
    __syncthreads();
    if (tid == 0) mask[bt] = s_any;
}

// ---------------------------------------------------------------------------
// K2: input-side gates. 8 rows/block, 256 threads, 3 cols/thread.
// ---------------------------------------------------------------------------
__global__ __launch_bounds__(256) void k_gates(
    const float* __restrict__ e,
    const float* __restrict__ wih_f, const float* __restrict__ bih_f,
    const float* __restrict__ wih_b, const float* __restrict__ bih_b,
    float* __restrict__ x3)
{
    const int r0  = blockIdx.x * 8;
    const int tid = threadIdx.x;
    __shared__ __align__(16) float se[8][DD];
    for (int i = tid; i < 8 * DD; i += 256)
        se[i >> 7][i & 127] = e[(size_t)(r0 + (i >> 7)) * DD + (i & 127)];
    __syncthreads();

    const float4* wp[3];
    float bias[3];
    #pragma unroll
    for (int cc = 0; cc < 3; ++cc) {
        int col = tid + cc * 256;
        if (col < G3) { wp[cc] = (const float4*)(wih_f + (size_t)col * DD);        bias[cc] = bih_f[col]; }
        else          { wp[cc] = (const float4*)(wih_b + (size_t)(col - G3) * DD); bias[cc] = bih_b[col - G3]; }
    }

    float acc[3][8];
    #pragma unroll
    for (int cc = 0; cc < 3; ++cc)
        #pragma unroll
        for (int r = 0; r < 8; ++r) acc[cc][r] = 0.f;

    for (int k4 = 0; k4 < DD / 4; ++k4) {
        float4 ev[8];
        #pragma unroll
        for (int r = 0; r < 8; ++r) ev[r] = *(const float4*)&se[r][4 * k4];
        #pragma unroll
        for (int cc = 0; cc < 3; ++cc) {
            float4 w = wp[cc][k4];
            #pragma unroll
            for (int r = 0; r < 8; ++r)
                acc[cc][r] += ev[r].x * w.x + ev[r].y * w.y + ev[r].z * w.z + ev[r].w * w.w;
        }
    }
    #pragma unroll
    for (int cc = 0; cc < 3; ++cc) {
        int col = tid + cc * 256;
        #pragma unroll
        for (int r = 0; r < 8; ++r)
            x3[(size_t)(r0 + r) * 768 + col] = acc[cc][r] + bias[cc];
    }
}

// ---------------------------------------------------------------------------
// K3: GRU, one block per (batch, dir). 1024 threads = 16 waves.
// ROOT CAUSE of the invariant ~111us across r1-r4: per-thread weight slabs of
// ~96-130 floats were DEMOTED by the register allocator (VGPR_Count 72-88 <
// what was asked) -> whh re-streamed from L1/L2 every step (~196KB/CU/step,
// L2-bound ~2700cyc/step). Fix: 8-way k-split so the slab is 48 floats
// (12 float4) per thread; total pressure ~90 VGPRs, within the 128 budget
// declared by __launch_bounds__(1024,4) -> weights stay register-resident.
// Thread (g = tid>>3, s = tid&7): rows {g, g+128, g+256}, cols [16s,16s+16).
// 3-level shfl_xor butterfly (1,2,4) -> every lane holds full r/z/n dots.
// x3 staged in 25-step LDS chunks; no global ops in the step loop.
// ---------------------------------------------------------------------------
__global__ __launch_bounds__(1024, 4) void k_gru(
    const float* __restrict__ x3,
    const float* __restrict__ whh_f, const float* __restrict__ bhh_f,
    const float* __restrict__ whh_b, const float* __restrict__ bhh_b,
    float* __restrict__ h_all)
{
    const int dir = blockIdx.x & 1;
    const int b   = blockIdx.x >> 1;
    const int tid = threadIdx.x;
    const int s   = tid & 7;    // k-slice 0..7 (cols 16s..16s+15)
    const int g   = tid >> 3;   // h element 0..127
    const float* whh = dir ? whh_b : whh_f;
    const float* bhh = dir ? bhh_b : bhh_f;

    float4 wr[4], wz[4], wn[4];
    {
        const float4* p0 = (const float4*)(whh + (size_t)(g      ) * DD + s * 16);
        const float4* p1 = (const float4*)(whh + (size_t)(g + 128) * DD + s * 16);
        const float4* p2 = (const float4*)(whh + (size_t)(g + 256) * DD + s * 16);
        #pragma unroll
        for (int k = 0; k < 4; ++k) { wr[k] = p0[k]; wz[k] = p1[k]; wn[k] = p2[k]; }
    }
    const float br = bhh[g], bz = bhh[g + 128], bn = bhh[g + 256];

    __shared__ __align__(16) float x_stage[CH * G3];   // 38.4 KB
    __shared__ __align__(16) float h_buf[2][DD];       // flat: b128 reads are conflict-free
    __shared__ __align__(16) float h_hist[TT * DD];    // 51.2 KB
    if (tid < DD) h_buf[0][tid] = 0.f;

    const float* xsrc = x3 + (size_t)b * TT * 768 + (size_t)dir * G3;
    float h_reg = 0.f;   // all 8 s-lanes of a g track identical h_reg

    for (int c = 0; c < TT / CH; ++c) {
        // ---- stage chunk c: coalesced global -> LDS (96 float4 per step row)
        for (int i = tid; i < CH * (G3 / 4); i += 1024) {
            int t_local = i / 96, col4 = i - t_local * 96;
            int t  = c * CH + t_local;
            int te = dir ? (TT - 1 - t) : t;
            *(float4*)&x_stage[t_local * G3 + col4 * 4] =
                *((const float4*)(xsrc + (size_t)te * 768) + col4);
        }
        __syncthreads();   // vmcnt drain once per 25 steps

        for (int t_local = 0; t_local < CH; ++t_local) {
            const int t  = c * CH + t_local;
            const int rb = t & 1, wb = rb ^ 1;
            const float* xp = &x_stage[t_local * G3];
            float xr = xp[g], xz = xp[DD + g], xn = xp[2 * DD + g];

            float ar = 0.f, az = 0.f, an = 0.f;
            #pragma unroll
            for (int k = 0; k < 4; ++k) {
                float4 hv = *(const float4*)&h_buf[rb][s * 16 + 4 * k];
                ar += wr[k].x * hv.x + wr[k].y * hv.y + wr[k].z * hv.z + wr[k].w * hv.w;
                az += wz[k].x * hv.x + wz[k].y * hv.y + wz[k].z * hv.z + wz[k].w * hv.w;
                an += wn[k].x * hv.x + wn[k].y * hv.y + wn[k].z * hv.z + wn[k].w * hv.w;
            }
            ar += __shfl_xor(ar, 1); az += __shfl_xor(az, 1); an += __shfl_xor(an, 1);
            ar += __shfl_xor(ar, 2); az += __shfl_xor(az, 2); an += __shfl_xor(an, 2);
            ar += __shfl_xor(ar, 4); az += __shfl_xor(az, 4); an += __shfl_xor(an, 4);

            float r    = 1.f / (1.f + __expf(-(xr + ar + br)));
            float z    = 1.f / (1.f + __expf(-(xz + az + bz)));
            float narg = xn + r * (an + bn);
            float et   = __expf(-2.f * fabsf(narg));
            float n    = (1.f - et) / (1.f + et);
            n = narg >= 0.f ? n : -n;
            float hnew = (1.f - z) * n + z * h_reg;
            h_reg = hnew;
            if (s == 0) {
                h_buf[wb][g] = hnew;
                h_hist[(dir ? TT - 1 - t : t) * DD + g] = hnew;
            }
            __syncthreads();   // lgkm-only drain
        }
    }

    // one coalesced dump of the whole history
    float4* dst = (float4*)(h_all + (size_t)(dir * BB + b) * TT * DD);
    const float4* src = (const float4*)h_hist;
    for (int i = tid; i < TT * DD / 4; i += 1024) dst[i] = src[i];
}

// ---------------------------------------------------------------------------
// K4: per-batch attention + h_last + combine + logits (fused).
// ---------------------------------------------------------------------------
__global__ __launch_bounds__(256) void k_attn(
    const float* __restrict__ h_all, const int* __restrict__ mask,
    const float* __restrict__ attn_w, const float* __restrict__ attn_b,
    const float* __restrict__ comb_w, const float* __restrict__ comb_b,
    const float* __restrict__ fc_w, const float* __restrict__ fc_b,
    float* __restrict__ out)
{
    const int b   = blockIdx.x;
    const int tid = threadIdx.x;
    __shared__ __align__(16) float s_h[TT * 256];   // [t][f]: f<128 hf, f>=128 hb
    __shared__ float s_aw[256];
    __shared__ float s_sc[128];
    __shared__ int   s_m[128];
    __shared__ float s_red[128];
    __shared__ __align__(16) float s_ch[512];
    __shared__ __align__(16) float s_feat[DD];

    const float* hf = h_all + (size_t)(0 * BB + b) * TT * DD;
    const float* hb = h_all + (size_t)(1 * BB + b) * TT * DD;
    {
        const float4* hf4 = (const float4*)hf;
        const float4* hb4 = (const float4*)hb;
        for (int i = tid; i < TT * DD / 4; i += 256) {
            int t = i >> 5, c = i & 31;
            *(float4*)&s_h[t * 256 +       c * 4] = hf4[i];
            *(float4*)&s_h[t * 256 + 128 + c * 4] = hb4[i];
        }
    }
    s_aw[tid] = attn_w[tid];
    int m = 0;
    if (tid < 128) {
        m = (tid < TT) ? mask[b * TT + tid] : 0;
        s_m[tid] = m;
    }
    __syncthreads();
    for (int s = 64; s > 0; s >>= 1) {
        if (tid < s) s_m[tid] += s_m[tid + s];
        __syncthreads();
    }
    const int last = s_m[0] - 1;

    float sc = -1e9f;
    if (tid < TT) {
        float a = attn_b[0];
        const float4* hf4 = (const float4*)(hf + (size_t)tid * DD);
        const float4* hb4 = (const float4*)(hb + (size_t)tid * DD);
        for (int k = 0; k < DD / 4; ++k) {
            float4 v = hf4[k];
            a += v.x * s_aw[4*k] + v.y * s_aw[4*k+1] + v.z * s_aw[4*k+2] + v.w * s_aw[4*k+3];
        }
        for (int k = 0; k < DD / 4; ++k) {
            float4 v = hb4[k];
            a += v.x * s_aw[DD+4*k] + v.y * s_aw[DD+4*k+1] + v.z * s_aw[DD+4*k+2] + v.w * s_aw[DD+4*k+3];
        }
        sc = m ? a : -1e9f;
    }
    if (tid < 128) { s_sc[tid] = sc; s_red[tid] = sc; }
    __syncthreads();
    for (int s = 64; s > 0; s >>= 1) {
        if (tid < s) s_red[tid] = fmaxf(s_red[tid], s_red[tid + s]);
        __syncthreads();
    }
    const float mx = s_red[0];
    __syncthreads();
    float ex = 0.f;
    if (tid < 128) { ex = __expf(s_sc[tid] - mx); s_sc[tid] = ex; s_red[tid] = ex; }
    __syncthreads();
    for (int s = 64; s > 0; s >>= 1) {
        if (tid < s) s_red[tid] += s_red[tid + s];
        __syncthreads();
    }
    const float inv = 1.f / s_red[0];
    __syncthreads();

    {
        float c0 = 0.f, c1 = 0.f, c2 = 0.f, c3 = 0.f;
        int t = 0;
        for (; t + 4 <= TT; t += 4) {
            c0 += s_sc[t+0] * s_h[(t+0) * 256 + tid];
            c1 += s_sc[t+1] * s_h[(t+1) * 256 + tid];
            c2 += s_sc[t+2] * s_h[(t+2) * 256 + tid];
            c3 += s_sc[t+3] * s_h[(t+3) * 256 + tid];
        }
        for (; t < TT; ++t) c0 += s_sc[t] * s_h[t * 256 + tid];
        s_ch[tid]       = ((c0 + c1) + (c2 + c3)) * inv;
        s_ch[256 + tid] = s_h[last * 256 + tid];
    }
    __syncthreads();

    if (tid < 128) {
        float a = comb_b[tid];
        const float4* cw = (const float4*)(comb_w + (size_t)tid * 512);
        #pragma unroll 4
        for (int k = 0; k < 128; ++k) {
            float4 w4 = cw[k];
            float4 v4 = *(const float4*)&s_ch[4 * k];
            a += w4.x * v4.x + w4.y * v4.y + w4.z * v4.z + w4.w * v4.w;
        }
        s_feat[tid] = tanhf(a);
    }
    __syncthreads();

    for (int o = tid; o < OUTN; o += 256) {
        float a0 = 0.f, a1 = 0.f;
        const float4* w4 = (const float4*)(fc_w + (size_t)o * DD);
        #pragma unroll
        for (int k = 0; k < DD / 8; ++k) {
            float4 w_0 = w4[2*k],   v_0 = *(const float4*)&s_feat[8*k];
            float4 w_1 = w4[2*k+1], v_1 = *(const float4*)&s_feat[8*k+4];
            a0 += w_0.x * v_0.x + w_0.y * v_0.y + w_0.z * v_0.z + w_0.w * v_0.w;
            a1 += w_1.x * v_1.x + w_1.y * v_1.y + w_1.z * v_1.z + w_1.w * v_1.w;
        }
        out[(size_t)b * OUTN + o] = a0 + a1 + fc_b[o];
    }
}

// ---------------------------------------------------------------------------
extern "C" void kernel_launch(void* const* d_in, const int* in_sizes, int n_in,
                              void* d_out, int out_size, void* d_ws, size_t ws_size,
                              hipStream_t stream)
{
    const float* x      = (const float*)d_in[0];
    const float* emb    = (const float*)d_in[1];
    const float* wih_f  = (const float*)d_in[2];
    const float* whh_f  = (const float*)d_in[3];
    const float* bih_f  = (const float*)d_in[4];
    const float* bhh_f  = (const float*)d_in[5];
    const float* wih_b  = (const float*)d_in[6];
    const float* whh_b  = (const float*)d_in[7];
    const float* bih_b  = (const float*)d_in[8];
    const float* bhh_b  = (const float*)d_in[9];
    const float* attn_w = (const float*)d_in[10];
    const float* attn_b = (const float*)d_in[11];
    const float* comb_w = (const float*)d_in[12];
    const float* comb_b = (const float*)d_in[13];
    const float* fc_w   = (const float*)d_in[14];
    const float* fc_b   = (const float*)d_in[15];
    float* out = (float*)d_out;

    float* ws    = (float*)d_ws;
    float* e     = ws;                    // 409600
    int*   mask  = (int*)(ws + 409600);   // 3200
    float* x3    = ws + 412800;           // 2457600
    float* h_all = ws + 2870400;          // 819200

    k_embed <<<BB * TT,      256, 0, stream>>>(x, emb, e, mask);
    k_gates <<<(BB * TT)/8,  256, 0, stream>>>(e, wih_f, bih_f, wih_b, bih_b, x3);
    k_gru   <<<2 * BB,      1024, 0, stream>>>(x3, whh_f, bhh_f, whh_b, bhh_b, h_all);
    k_attn  <<<BB,           256, 0, stream>>>(h_all, mask, attn_w, attn_b,
                                               comb_w, comb_b, fc_w, fc_b, out);
}

// Round 6
// 395.833 us; speedup vs baseline: 1.0823x; 1.0823x over previous
//
#include <hip/hip_runtime.h>
#include <math.h>

#define BB 32
#define TT 100
#define VV 10000
#define DD 128
#define OUTN 1000
#define G3 384
#define CH 50    // GRU steps per LDS-staged x3 chunk

// ---------------------------------------------------------------------------
// K1: sparse embedding sum  e[b,t,:] = sum_{v: x!=0} x[b,t,v] * emb[v,:]
// ---------------------------------------------------------------------------
__global__ __launch_bounds__(256) void k_embed(
    const float* __restrict__ x, const float* __restrict__ emb,
    float* __restrict__ e, int* __restrict__ mask)
{
    const int bt  = blockIdx.x;
    const int tid = threadIdx.x;
    __shared__ int   s_cnt;
    __shared__ int   s_any;
    __shared__ int   s_idx[256];
    __shared__ float s_val[256];
    if (tid == 0) { s_cnt = 0; s_any = 0; }
    __syncthreads();

    const float4* x4 = (const float4*)(x + (size_t)bt * VV);
    float4 v[10];
    #pragma unroll
    for (int k = 0; k < 10; ++k) {
        int i = tid + k * 256;
        int ic = i < 2500 ? i : 2499;
        v[k] = x4[ic];
        if (i >= 2500) { v[k].x = 0.f; v[k].y = 0.f; v[k].z = 0.f; v[k].w = 0.f; }
    }
    #pragma unroll
    for (int k = 0; k < 10; ++k) {
        int base = (tid + k * 256) * 4;
        if (v[k].x != 0.f) { int p = atomicAdd(&s_cnt, 1); if (p < 256) { s_idx[p] = base+0; s_val[p] = v[k].x; } }
        if (v[k].y != 0.f) { int p = atomicAdd(&s_cnt, 1); if (p < 256) { s_idx[p] = base+1; s_val[p] = v[k].y; } }
        if (v[k].z != 0.f) { int p = atomicAdd(&s_cnt, 1); if (p < 256) { s_idx[p] = base+2; s_val[p] = v[k].z; } }
        if (v[k].w != 0.f) { int p = atomicAdd(&s_cnt, 1); if (p < 256) { s_idx[p] = base+3; s_val[p] = v[k].w; } }
    }
    __syncthreads();
    int cnt = s_cnt; if (cnt > 256) cnt = 256;
    if (tid < DD) {
        float a0 = 0.f, a1 = 0.f, a2 = 0.f, a3 = 0.f;
        int i = 0;
        for (; i + 4 <= cnt; i += 4) {
            a0 += s_val[i+0] * emb[(size_t)s_idx[i+0] * DD + tid];
            a1 += s_val[i+1] * emb[(size_t)s_idx[i+1] * DD + tid];
            a2 += s_val[i+2] * emb[(size_t)s_idx[i+2] * DD + tid];
            a3 += s_val[i+3] * emb[(size_t)s_idx[i+3] * DD + tid];
        }
        for (; i < cnt; ++i)
            a0 += s_val[i] * emb[(size_t)s_idx[i] * DD + tid];
        float acc = (a0 + a1) + (a2 + a3);
        e[(size_t)bt * DD + tid] = acc;
        if (acc != 0.f) s_any = 1;
    }
    __syncthreads();
    if (tid == 0) mask[bt] = s_any;
}

// ---------------------------------------------------------------------------
// K2: input-side gates. 8 rows/block, 256 threads, 3 cols/thread.
// ---------------------------------------------------------------------------
__global__ __launch_bounds__(256) void k_gates(
    const float* __restrict__ e,
    const float* __restrict__ wih_f, const float* __restrict__ bih_f,
    const float* __restrict__ wih_b, const float* __restrict__ bih_b,
    float* __restrict__ x3)
{
    const int r0  = blockIdx.x * 8;
    const int tid = threadIdx.x;
    __shared__ __align__(16) float se[8][DD];
    for (int i = tid; i < 8 * DD; i += 256)
        se[i >> 7][i & 127] = e[(size_t)(r0 + (i >> 7)) * DD + (i & 127)];
    __syncthreads();

    const float4* wp[3];
    float bias[3];
    #pragma unroll
    for (int cc = 0; cc < 3; ++cc) {
        int col = tid + cc * 256;
        if (col < G3) { wp[cc] = (const float4*)(wih_f + (size_t)col * DD);        bias[cc] = bih_f[col]; }
        else          { wp[cc] = (const float4*)(wih_b + (size_t)(col - G3) * DD); bias[cc] = bih_b[col - G3]; }
    }

    float acc[3][8];
    #pragma unroll
    for (int cc = 0; cc < 3; ++cc)
        #pragma unroll
        for (int r = 0; r < 8; ++r) acc[cc][r] = 0.f;

    for (int k4 = 0; k4 < DD / 4; ++k4) {
        float4 ev[8];
        #pragma unroll
        for (int r = 0; r < 8; ++r) ev[r] = *(const float4*)&se[r][4 * k4];
        #pragma unroll
        for (int cc = 0; cc < 3; ++cc) {
            float4 w = wp[cc][k4];
            #pragma unroll
            for (int r = 0; r < 8; ++r)
                acc[cc][r] += ev[r].x * w.x + ev[r].y * w.y + ev[r].z * w.z + ev[r].w * w.w;
        }
    }
    #pragma unroll
    for (int cc = 0; cc < 3; ++cc) {
        int col = tid + cc * 256;
        #pragma unroll
        for (int r = 0; r < 8; ++r)
            x3[(size_t)(r0 + r) * 768 + col] = acc[cc][r] + bias[cc];
    }
}

// ---------------------------------------------------------------------------
// K3: GRU, one block per (batch, dir). 512 threads = 8 waves.
// ROOT CAUSE (r1-r5): the register allocator DEMOTED the hoisted whh weight
// loads back into the step loop (VGPR_Count 52-88 < weight-slab size in every
// round) -> 196 KB/step re-streamed from L2, serialized by the barrier's
// vmcnt drain (~2700 cyc/step, invariant across 4 structures).
// FIX: opaque asm pin (asm volatile "" : "+v") on all 96 weight floats after
// the hoisted load -> non-rematerializable -> allocator must keep them in
// VGPRs. __launch_bounds__(512,2) gives a 256-VGPR budget (96 pinned + ~50
// live, no scratch). x3 LDS-staged (no global ops in the step loop);
// h_buf padded [4][36] (conflict-free); 2-level shfl_xor butterfly.
// VALIDATION: VGPR_Count should jump to ~150+; if not, pin failed.
// ---------------------------------------------------------------------------
__global__ __launch_bounds__(512, 2) void k_gru(
    const float* __restrict__ x3,
    const float* __restrict__ whh_f, const float* __restrict__ bhh_f,
    const float* __restrict__ whh_b, const float* __restrict__ bhh_b,
    float* __restrict__ h_all)
{
    const int dir = blockIdx.x & 1;
    const int b   = blockIdx.x >> 1;
    const int tid = threadIdx.x;
    const int s   = tid & 3;    // k-slice 0..3 (cols 32s..32s+31)
    const int g   = tid >> 2;   // h element 0..127
    const float* whh = dir ? whh_b : whh_f;
    const float* bhh = dir ? bhh_b : bhh_f;

    float4 wr[8], wz[8], wn[8];
    {
        const float4* p0 = (const float4*)(whh + (size_t)(g      ) * DD + s * 32);
        const float4* p1 = (const float4*)(whh + (size_t)(g + 128) * DD + s * 32);
        const float4* p2 = (const float4*)(whh + (size_t)(g + 256) * DD + s * 32);
        #pragma unroll
        for (int k = 0; k < 8; ++k) { wr[k] = p0[k]; wz[k] = p1[k]; wn[k] = p2[k]; }
    }
    // ---- PIN: make weights opaque so the allocator cannot sink/remat the
    // loads into the step loop. Forces true register residency.
    #pragma unroll
    for (int k = 0; k < 8; ++k) {
        asm volatile("" : "+v"(wr[k].x), "+v"(wr[k].y), "+v"(wr[k].z), "+v"(wr[k].w));
        asm volatile("" : "+v"(wz[k].x), "+v"(wz[k].y), "+v"(wz[k].z), "+v"(wz[k].w));
        asm volatile("" : "+v"(wn[k].x), "+v"(wn[k].y), "+v"(wn[k].z), "+v"(wn[k].w));
    }
    const float br = bhh[g], bz = bhh[g + 128], bn = bhh[g + 256];

    __shared__ __align__(16) float x_stage[CH * G3];   // 76.8 KB
    __shared__ __align__(16) float h_buf[2][144];      // h[j] at [(j>>5)*36+(j&31)]
    __shared__ __align__(16) float h_hist[TT * DD];    // 51.2 KB
    if (tid < 144) h_buf[0][tid] = 0.f;

    const float* xsrc = x3 + (size_t)b * TT * 768 + (size_t)dir * G3;
    float h_reg = 0.f;   // all 4 s-lanes of a g track identical h_reg

    for (int c = 0; c < TT / CH; ++c) {
        // ---- stage chunk c: coalesced global -> LDS (96 float4 per step row)
        for (int i = tid; i < CH * (G3 / 4); i += 512) {
            int t_local = i / 96, col4 = i - t_local * 96;
            int t  = c * CH + t_local;
            int te = dir ? (TT - 1 - t) : t;
            *(float4*)&x_stage[t_local * G3 + col4 * 4] =
                *((const float4*)(xsrc + (size_t)te * 768) + col4);
        }
        __syncthreads();   // vmcnt drain once per 50 steps

        for (int t_local = 0; t_local < CH; ++t_local) {
            const int t  = c * CH + t_local;
            const int rb = t & 1, wb = rb ^ 1;
            const float* xp = &x_stage[t_local * G3];
            float xr = xp[g], xz = xp[DD + g], xn = xp[2 * DD + g];

            float ar = 0.f, az = 0.f, an = 0.f;
            #pragma unroll
            for (int k = 0; k < 8; ++k) {
                float4 hv = *(const float4*)&h_buf[rb][s * 36 + 4 * k];
                ar += wr[k].x * hv.x + wr[k].y * hv.y + wr[k].z * hv.z + wr[k].w * hv.w;
                az += wz[k].x * hv.x + wz[k].y * hv.y + wz[k].z * hv.z + wz[k].w * hv.w;
                an += wn[k].x * hv.x + wn[k].y * hv.y + wn[k].z * hv.z + wn[k].w * hv.w;
            }
            ar += __shfl_xor(ar, 1); az += __shfl_xor(az, 1); an += __shfl_xor(an, 1);
            ar += __shfl_xor(ar, 2); az += __shfl_xor(az, 2); an += __shfl_xor(an, 2);

            float r    = 1.f / (1.f + __expf(-(xr + ar + br)));
            float z    = 1.f / (1.f + __expf(-(xz + az + bz)));
            float narg = xn + r * (an + bn);
            float et   = __expf(-2.f * fabsf(narg));
            float n    = (1.f - et) / (1.f + et);
            n = narg >= 0.f ? n : -n;
            float hnew = (1.f - z) * n + z * h_reg;
            h_reg = hnew;
            if (s == 0) {
                h_buf[wb][(g >> 5) * 36 + (g & 31)] = hnew;
                h_hist[(dir ? TT - 1 - t : t) * DD + g] = hnew;
            }
            __syncthreads();   // lgkm-only drain: no global ops in flight
        }
    }

    // one coalesced dump of the whole history
    float4* dst = (float4*)(h_all + (size_t)(dir * BB + b) * TT * DD);
    const float4* src = (const float4*)h_hist;
    for (int i = tid; i < TT * DD / 4; i += 512) dst[i] = src[i];
}

// ---------------------------------------------------------------------------
// K4: per-batch attention + h_last + combine + logits (fused).
// ---------------------------------------------------------------------------
__global__ __launch_bounds__(256) void k_attn(
    const float* __restrict__ h_all, const int* __restrict__ mask,
    const float* __restrict__ attn_w, const float* __restrict__ attn_b,
    const float* __restrict__ comb_w, const float* __restrict__ comb_b,
    const float* __restrict__ fc_w, const float* __restrict__ fc_b,
    float* __restrict__ out)
{
    const int b   = blockIdx.x;
    const int tid = threadIdx.x;
    __shared__ __align__(16) float s_h[TT * 256];   // [t][f]: f<128 hf, f>=128 hb
    __shared__ float s_aw[256];
    __shared__ float s_sc[128];
    __shared__ int   s_m[128];
    __shared__ float s_red[128];
    __shared__ __align__(16) float s_ch[512];
    __shared__ __align__(16) float s_feat[DD];

    const float* hf = h_all + (size_t)(0 * BB + b) * TT * DD;
    const float* hb = h_all + (size_t)(1 * BB + b) * TT * DD;
    {
        const float4* hf4 = (const float4*)hf;
        const float4* hb4 = (const float4*)hb;
        for (int i = tid; i < TT * DD / 4; i += 256) {
            int t = i >> 5, c = i & 31;
            *(float4*)&s_h[t * 256 +       c * 4] = hf4[i];
            *(float4*)&s_h[t * 256 + 128 + c * 4] = hb4[i];
        }
    }
    s_aw[tid] = attn_w[tid];
    int m = 0;
    if (tid < 128) {
        m = (tid < TT) ? mask[b * TT + tid] : 0;
        s_m[tid] = m;
    }
    __syncthreads();
    for (int s = 64; s > 0; s >>= 1) {
        if (tid < s) s_m[tid] += s_m[tid + s];
        __syncthreads();
    }
    const int last = s_m[0] - 1;

    float sc = -1e9f;
    if (tid < TT) {
        float a = attn_b[0];
        const float4* hf4 = (const float4*)(hf + (size_t)tid * DD);
        const float4* hb4 = (const float4*)(hb + (size_t)tid * DD);
        for (int k = 0; k < DD / 4; ++k) {
            float4 v = hf4[k];
            a += v.x * s_aw[4*k] + v.y * s_aw[4*k+1] + v.z * s_aw[4*k+2] + v.w * s_aw[4*k+3];
        }
        for (int k = 0; k < DD / 4; ++k) {
            float4 v = hb4[k];
            a += v.x * s_aw[DD+4*k] + v.y * s_aw[DD+4*k+1] + v.z * s_aw[DD+4*k+2] + v.w * s_aw[DD+4*k+3];
        }
        sc = m ? a : -1e9f;
    }
    if (tid < 128) { s_sc[tid] = sc; s_red[tid] = sc; }
    __syncthreads();
    for (int s = 64; s > 0; s >>= 1) {
        if (tid < s) s_red[tid] = fmaxf(s_red[tid], s_red[tid + s]);
        __syncthreads();
    }
    const float mx = s_red[0];
    __syncthreads();
    float ex = 0.f;
    if (tid < 128) { ex = __expf(s_sc[tid] - mx); s_sc[tid] = ex; s_red[tid] = ex; }
    __syncthreads();
    for (int s = 64; s > 0; s >>= 1) {
        if (tid < s) s_red[tid] += s_red[tid + s];
        __syncthreads();
    }
    const float inv = 1.f / s_red[0];
    __syncthreads();

    {
        float c0 = 0.f, c1 = 0.f, c2 = 0.f, c3 = 0.f;
        int t = 0;
        for (; t + 4 <= TT; t += 4) {
            c0 += s_sc[t+0] * s_h[(t+0) * 256 + tid];
            c1 += s_sc[t+1] * s_h[(t+1) * 256 + tid];
            c2 += s_sc[t+2] * s_h[(t+2) * 256 + tid];
            c3 += s_sc[t+3] * s_h[(t+3) * 256 + tid];
        }
        for (; t < TT; ++t) c0 += s_sc[t] * s_h[t * 256 + tid];
        s_ch[tid]       = ((c0 + c1) + (c2 + c3)) * inv;
        s_ch[256 + tid] = s_h[last * 256 + tid];
    }
    __syncthreads();

    if (tid < 128) {
        float a = comb_b[tid];
        const float4* cw = (const float4*)(comb_w + (size_t)tid * 512);
        #pragma unroll 4
        for (int k = 0; k < 128; ++k) {
            float4 w4 = cw[k];
            float4 v4 = *(const float4*)&s_ch[4 * k];
            a += w4.x * v4.x + w4.y * v4.y + w4.z * v4.z + w4.w * v4.w;
        }
        s_feat[tid] = tanhf(a);
    }
    __syncthreads();

    for (int o = tid; o < OUTN; o += 256) {
        float a0 = 0.f, a1 = 0.f;
        const float4* w4 = (const float4*)(fc_w + (size_t)o * DD);
        #pragma unroll
        for (int k = 0; k < DD / 8; ++k) {
            float4 w_0 = w4[2*k],   v_0 = *(const float4*)&s_feat[8*k];
            float4 w_1 = w4[2*k+1], v_1 = *(const float4*)&s_feat[8*k+4];
            a0 += w_0.x * v_0.x + w_0.y * v_0.y + w_0.z * v_0.z + w_0.w * v_0.w;
            a1 += w_1.x * v_1.x + w_1.y * v_1.y + w_1.z * v_1.z + w_1.w * v_1.w;
        }
        out[(size_t)b * OUTN + o] = a0 + a1 + fc_b[o];
    }
}

// ---------------------------------------------------------------------------
extern "C" void kernel_launch(void* const* d_in, const int* in_sizes, int n_in,
                              void* d_out, int out_size, void* d_ws, size_t ws_size,
                              hipStream_t stream)
{
    const float* x      = (const float*)d_in[0];
    const float* emb    = (const float*)d_in[1];
    const float* wih_f  = (const float*)d_in[2];
    const float* whh_f  = (const float*)d_in[3];
    const float* bih_f  = (const float*)d_in[4];
    const float* bhh_f  = (const float*)d_in[5];
    const float* wih_b  = (const float*)d_in[6];
    const float* whh_b  = (const float*)d_in[7];
    const float* bih_b  = (const float*)d_in[8];
    const float* bhh_b  = (const float*)d_in[9];
    const float* attn_w = (const float*)d_in[10];
    const float* attn_b = (const float*)d_in[11];
    const float* comb_w = (const float*)d_in[12];
    const float* comb_b = (const float*)d_in[13];
    const float* fc_w   = (const float*)d_in[14];
    const float* fc_b   = (const float*)d_in[15];
    float* out = (float*)d_out;

    float* ws    = (float*)d_ws;
    float* e     = ws;                    // 409600
    int*   mask  = (int*)(ws + 409600);   // 3200
    float* x3    = ws + 412800;           // 2457600
    float* h_all = ws + 2870400;          // 819200

    k_embed <<<BB * TT,      256, 0, stream>>>(x, emb, e, mask);
    k_gates <<<(BB * TT)/8,  256, 0, stream>>>(e, wih_f, bih_f, wih_b, bih_b, x3);
    k_gru   <<<2 * BB,       512, 0, stream>>>(x3, whh_f, bhh_f, whh_b, bhh_b, h_all);
    k_attn  <<<BB,           256, 0, stream>>>(h_all, mask, attn_w, attn_b,
                                               comb_w, comb_b, fc_w, fc_b, out);
}